// Round 1
// baseline (2213.177 us; speedup 1.0000x reference)
//
#include <hip/hip_runtime.h>
#include <math.h>

// SLSTM block step, fp32.
// B=2048 H=4096 NH=4 HS=1024 convK=4
// d_out slots (floats, each B*H unless noted):
//   [0*BH) out | [1*BH,4*BH) new_conv_state (B,3,H) | [4*BH) y | [5*BH) cell
//   [6*BH) norm | [7*BH) max
// Stash plan (no d_ws needed):
//   x_act -> out slot (consumed by gemm pass 1, overwritten by post kernel)
//   xn    -> new_conv_state[:,2,:]  (it IS that output; gemm pass 2 reads it, stride 3H)
//   gate pre-acts i,f,z,o -> y,cell,norm,max slots (consumed+overwritten in place by post)

#define Bn 2048
#define Hn 4096
#define NHn 4
#define HSn 1024

// ---------------------------------------------------------------- prep ------
// LayerNorm + conv window + SiLU. One block per batch row.
__global__ __launch_bounds__(256) void prep_kernel(
    const float* __restrict__ x, const float* __restrict__ cs,
    const float* __restrict__ ln_w, const float* __restrict__ conv_w,
    const float* __restrict__ conv_b, float* __restrict__ dout) {
  const int b = blockIdx.x;
  const int t = threadIdx.x;
  const float* xr = x + (size_t)b * Hn;

  float4 xv[4];
  float s = 0.f, s2 = 0.f;
#pragma unroll
  for (int i = 0; i < 4; ++i) {
    xv[i] = *reinterpret_cast<const float4*>(xr + i * 1024 + t * 4);
    s += xv[i].x + xv[i].y + xv[i].z + xv[i].w;
    s2 += xv[i].x * xv[i].x + xv[i].y * xv[i].y + xv[i].z * xv[i].z +
          xv[i].w * xv[i].w;
  }
#pragma unroll
  for (int off = 32; off >= 1; off >>= 1) {
    s += __shfl_down(s, off);
    s2 += __shfl_down(s2, off);
  }
  __shared__ float red[10];
  const int lane = t & 63, wv = t >> 6;
  if (lane == 0) { red[wv] = s; red[4 + wv] = s2; }
  __syncthreads();
  if (t == 0) {
    float ts = red[0] + red[1] + red[2] + red[3];
    float ts2 = red[4] + red[5] + red[6] + red[7];
    float mean = ts * (1.f / Hn);
    float var = ts2 * (1.f / Hn) - mean * mean;
    red[8] = mean;
    red[9] = rsqrtf(var + 1e-5f);
  }
  __syncthreads();
  const float mean = red[8], rstd = red[9];

  float* xact_out = dout;                       // stash in "out" slot
  float* ncs = dout + (size_t)Bn * Hn;          // new_conv_state (B,3,H)

#pragma unroll
  for (int i = 0; i < 4; ++i) {
    const int h = i * 1024 + t * 4;
    float lw[4], cs0[4], cs1[4], cs2[4], cb[4];
    *(float4*)lw = *(const float4*)(ln_w + h);
    *(float4*)cs0 = *(const float4*)(cs + ((size_t)b * 3 + 0) * Hn + h);
    *(float4*)cs1 = *(const float4*)(cs + ((size_t)b * 3 + 1) * Hn + h);
    *(float4*)cs2 = *(const float4*)(cs + ((size_t)b * 3 + 2) * Hn + h);
    *(float4*)cb = *(const float4*)(conv_b + h);
    const float xvi[4] = {xv[i].x, xv[i].y, xv[i].z, xv[i].w};
    float xnv[4], xav[4];
#pragma unroll
    for (int j = 0; j < 4; ++j) {
      const float xnj = (xvi[j] - mean) * rstd * lw[j];
      float cw[4];
      *(float4*)cw = *(const float4*)(conv_w + (size_t)(h + j) * 4);
      const float xc =
          cs0[j] * cw[0] + cs1[j] * cw[1] + cs2[j] * cw[2] + xnj * cw[3] + cb[j];
      xav[j] = xc / (1.f + expf(-xc));  // silu
      xnv[j] = xnj;
    }
    *(float4*)(xact_out + (size_t)b * Hn + h) = *(float4*)xav;
    *(float4*)(ncs + ((size_t)b * 3 + 0) * Hn + h) = *(float4*)cs1;
    *(float4*)(ncs + ((size_t)b * 3 + 1) * Hn + h) = *(float4*)cs2;
    *(float4*)(ncs + ((size_t)b * 3 + 2) * Hn + h) = *(float4*)xnv;
  }
}

// ---------------------------------------------------------------- gemm ------
// Computes, for one gate pair (g0,g1) and all heads:
//   Og[b, head*HS+k] = sum_h Ain[b,h]*Wg_in[head,k,h] + Ast[b,h]*Wg_st[head,k,h] + bias
// Tiles: BM=128 (batch) x BN=64 (k) x BK=16, 256 threads, thread tile 8x4 per gate.
// Both operands are h(K)-contiguous -> transposed LDS staging for both.
__global__ __launch_bounds__(256) void gemm_pair(
    const float* __restrict__ Ain, int lda_in, const float* __restrict__ Ast,
    const float* __restrict__ W0in, const float* __restrict__ W0st,
    const float* __restrict__ W1in, const float* __restrict__ W1st,
    const float* __restrict__ bias0, const float* __restrict__ bias1,
    float* __restrict__ O0, float* __restrict__ O1) {
  // XCD-chunked swizzle: 16 consecutive logical blocks (one (head,nt) weight
  // panel, all M-tiles) land on the same XCD -> weight panel stays in its L2.
  const int bid = blockIdx.x;                 // 0..1023
  const int swz = (bid & 7) * 128 + (bid >> 3);
  const int head = swz >> 8;
  const int rem = swz & 255;
  const int nt = rem >> 4;
  const int mt = rem & 15;
  const int bm0 = mt * 128;
  const int kn0 = nt * 64;

  const int t = threadIdx.x;

  __shared__ float sA[16][132];   // [BK][BM+4] transposed, pad keeps 16B align
  __shared__ float sB[2][16][68]; // per-gate [BK][BN+4]

  // staging thread mapping
  const int r0 = t >> 2;           // 0..63 (A rows)
  const int c4 = (t & 3) * 4;      // 0,4,8,12 (h within tile)
  const int gg = t >> 7;           // which gate this thread stages
  const int tt = t & 127;
  const int br = tt >> 2;          // 0..31 (W rows)
  const int bc = (tt & 3) * 4;

  // compute thread mapping (16x16 grid of 8x4 micro-tiles)
  const int tm = (t >> 4) * 8;
  const int tn = (t & 15) * 4;

  float acc0[8][4], acc1[8][4];
#pragma unroll
  for (int i = 0; i < 8; ++i)
#pragma unroll
    for (int j = 0; j < 4; ++j) { acc0[i][j] = 0.f; acc1[i][j] = 0.f; }

#pragma unroll 1
  for (int ph = 0; ph < 2; ++ph) {
    const float* Ap = (ph ? Ast : Ain) + (size_t)head * HSn;
    const int lda = ph ? Hn : lda_in;
    const float* Wg0 = (ph ? W0st : W0in) + (size_t)head * HSn * HSn;
    const float* Wg1 = (ph ? W1st : W1in) + (size_t)head * HSn * HSn;
    const float* Wgg = gg ? Wg1 : Wg0;

#pragma unroll 1
    for (int h0 = 0; h0 < HSn; h0 += 16) {
      const float* ap = Ap + (size_t)(bm0 + r0) * lda + h0 + c4;
      const float4 av0 = *reinterpret_cast<const float4*>(ap);
      const float4 av1 = *reinterpret_cast<const float4*>(ap + (size_t)64 * lda);
      const float* wp = Wgg + (size_t)(kn0 + br) * HSn + h0 + bc;
      const float4 bv0 = *reinterpret_cast<const float4*>(wp);
      const float4 bv1 = *reinterpret_cast<const float4*>(wp + 32 * HSn);

      sA[c4 + 0][r0] = av0.x; sA[c4 + 1][r0] = av0.y;
      sA[c4 + 2][r0] = av0.z; sA[c4 + 3][r0] = av0.w;
      sA[c4 + 0][r0 + 64] = av1.x; sA[c4 + 1][r0 + 64] = av1.y;
      sA[c4 + 2][r0 + 64] = av1.z; sA[c4 + 3][r0 + 64] = av1.w;

      sB[gg][bc + 0][br] = bv0.x; sB[gg][bc + 1][br] = bv0.y;
      sB[gg][bc + 2][br] = bv0.z; sB[gg][bc + 3][br] = bv0.w;
      sB[gg][bc + 0][br + 32] = bv1.x; sB[gg][bc + 1][br + 32] = bv1.y;
      sB[gg][bc + 2][br + 32] = bv1.z; sB[gg][bc + 3][br + 32] = bv1.w;

      __syncthreads();

#pragma unroll
      for (int kk = 0; kk < 16; ++kk) {
        float av[8], b0v[4], b1v[4];
        *reinterpret_cast<float4*>(&av[0]) =
            *reinterpret_cast<const float4*>(&sA[kk][tm]);
        *reinterpret_cast<float4*>(&av[4]) =
            *reinterpret_cast<const float4*>(&sA[kk][tm + 4]);
        *reinterpret_cast<float4*>(&b0v[0]) =
            *reinterpret_cast<const float4*>(&sB[0][kk][tn]);
        *reinterpret_cast<float4*>(&b1v[0]) =
            *reinterpret_cast<const float4*>(&sB[1][kk][tn]);
#pragma unroll
        for (int i = 0; i < 8; ++i)
#pragma unroll
          for (int j = 0; j < 4; ++j) {
            acc0[i][j] = fmaf(av[i], b0v[j], acc0[i][j]);
            acc1[i][j] = fmaf(av[i], b1v[j], acc1[i][j]);
          }
      }
      __syncthreads();
    }
  }

  const int col = head * HSn + kn0 + tn;
  float b0v[4], b1v[4];
  *(float4*)b0v = *(const float4*)(bias0 + col);
  *(float4*)b1v = *(const float4*)(bias1 + col);
#pragma unroll
  for (int i = 0; i < 8; ++i) {
    const size_t row = (size_t)(bm0 + tm + i);
    float o0[4], o1[4];
#pragma unroll
    for (int j = 0; j < 4; ++j) {
      o0[j] = acc0[i][j] + b0v[j];
      o1[j] = acc1[i][j] + b1v[j];
    }
    *reinterpret_cast<float4*>(O0 + row * Hn + col) = *(float4*)o0;
    *reinterpret_cast<float4*>(O1 + row * Hn + col) = *(float4*)o1;
  }
}

// ---------------------------------------------------------------- post ------
// Gate nonlinearities + cell update + GroupNorm(+skip). One block per (b,head).
// Reads gate pre-acts from y/cell/norm/max slots, overwrites them in place.
__global__ __launch_bounds__(256) void post_kernel(
    const float* __restrict__ x, const float* __restrict__ cell_state,
    const float* __restrict__ norm_state, const float* __restrict__ max_state,
    const float* __restrict__ gn_w, const float* __restrict__ gn_b,
    float* __restrict__ dout) {
  const size_t BH = (size_t)Bn * Hn;
  const int blk = blockIdx.x;
  const int b = blk >> 2;
  const int n = blk & 3;
  const int t = threadIdx.x;
  const int col = n * HSn + t * 4;
  const size_t off = (size_t)b * Hn + col;

  float iv[4], fv[4], zv[4], ov[4], csv[4], nsv[4], msv[4], xv[4];
  *(float4*)iv = *(const float4*)(dout + 4 * BH + off);
  *(float4*)fv = *(const float4*)(dout + 5 * BH + off);
  *(float4*)zv = *(const float4*)(dout + 6 * BH + off);
  *(float4*)ov = *(const float4*)(dout + 7 * BH + off);
  *(float4*)csv = *(const float4*)(cell_state + off);
  *(float4*)nsv = *(const float4*)(norm_state + off);
  *(float4*)msv = *(const float4*)(max_state + off);
  *(float4*)xv = *(const float4*)(x + off);

  float yv[4], cnv[4], nnv[4], mnv[4];
  float s = 0.f, s2 = 0.f;
#pragma unroll
  for (int j = 0; j < 4; ++j) {
    const float fj = fv[j];
    const float ls =
        (fj >= 0.f) ? -log1pf(expf(-fj)) : (fj - log1pf(expf(fj)));
    const float lfm = msv[j] + ls;       // max_state + log_sigmoid(f)
    const float mn = fmaxf(iv[j], lfm);  // max_new
    const float ig = expf(iv[j] - mn);
    const float fg = expf(lfm - mn);
    const float cn = fg * csv[j] + ig * tanhf(zv[j]);
    const float nn = fg * nsv[j] + ig;
    const float so = 1.f / (1.f + expf(-ov[j]));
    const float y = so * cn / (nn + 1e-6f);
    yv[j] = y; cnv[j] = cn; nnv[j] = nn; mnv[j] = mn;
    s += y; s2 += y * y;
  }
  *(float4*)(dout + 4 * BH + off) = *(float4*)yv;
  *(float4*)(dout + 5 * BH + off) = *(float4*)cnv;
  *(float4*)(dout + 6 * BH + off) = *(float4*)nnv;
  *(float4*)(dout + 7 * BH + off) = *(float4*)mnv;

#pragma unroll
  for (int o2 = 32; o2 >= 1; o2 >>= 1) {
    s += __shfl_down(s, o2);
    s2 += __shfl_down(s2, o2);
  }
  __shared__ float red[10];
  const int lane = t & 63, wv = t >> 6;
  if (lane == 0) { red[wv] = s; red[4 + wv] = s2; }
  __syncthreads();
  if (t == 0) {
    float ts = red[0] + red[1] + red[2] + red[3];
    float ts2 = red[4] + red[5] + red[6] + red[7];
    float mean = ts * (1.f / HSn);
    float var = ts2 * (1.f / HSn) - mean * mean;
    red[8] = mean;
    red[9] = rsqrtf(var + 1e-5f);
  }
  __syncthreads();
  const float gm = red[8], grs = red[9];
  float gw[4], gb[4], outv[4];
  *(float4*)gw = *(const float4*)(gn_w + col);
  *(float4*)gb = *(const float4*)(gn_b + col);
#pragma unroll
  for (int j = 0; j < 4; ++j)
    outv[j] = (yv[j] - gm) * grs * gw[j] + gb[j] + xv[j];
  *(float4*)(dout + off) = *(float4*)outv;
}

// --------------------------------------------------------------- launch -----
extern "C" void kernel_launch(void* const* d_in, const int* in_sizes, int n_in,
                              void* d_out, int out_size, void* d_ws,
                              size_t ws_size, hipStream_t stream) {
  const float* x = (const float*)d_in[0];
  const float* cs = (const float*)d_in[1];
  const float* rst = (const float*)d_in[2];
  const float* cell = (const float*)d_in[3];
  const float* norm = (const float*)d_in[4];
  const float* maxs = (const float*)d_in[5];
  const float* ln_w = (const float*)d_in[6];
  const float* conv_w = (const float*)d_in[7];
  const float* conv_b = (const float*)d_in[8];
  const float* Wi_in = (const float*)d_in[9];
  const float* Wf_in = (const float*)d_in[10];
  const float* Wz_in = (const float*)d_in[11];
  const float* Wo_in = (const float*)d_in[12];
  const float* Wi_st = (const float*)d_in[13];
  const float* Wf_st = (const float*)d_in[14];
  const float* Wz_st = (const float*)d_in[15];
  const float* Wo_st = (const float*)d_in[16];
  const float* bi = (const float*)d_in[17];
  const float* bf = (const float*)d_in[18];
  const float* bz = (const float*)d_in[19];
  const float* bo = (const float*)d_in[20];
  const float* gn_w = (const float*)d_in[21];
  const float* gn_b = (const float*)d_in[22];

  float* out = (float*)d_out;
  const size_t BH = (size_t)Bn * Hn;
  float* xact = out;                      // stash
  float* ncs = out + BH;                  // real output (B,3,H)
  const float* xn = ncs + 2 * (size_t)Hn; // = new_conv_state[:,2,:], stride 3H
  float* slot_i = out + 4 * BH;
  float* slot_f = out + 5 * BH;
  float* slot_z = out + 6 * BH;
  float* slot_o = out + 7 * BH;

  hipLaunchKernelGGL(prep_kernel, dim3(Bn), dim3(256), 0, stream, x, cs, ln_w,
                     conv_w, conv_b, out);
  hipLaunchKernelGGL(gemm_pair, dim3(1024), dim3(256), 0, stream, xact, Hn, rst,
                     Wi_in, Wi_st, Wf_in, Wf_st, bi, bf, slot_i, slot_f);
  hipLaunchKernelGGL(gemm_pair, dim3(1024), dim3(256), 0, stream, xn, 3 * Hn,
                     rst, Wz_in, Wz_st, Wo_in, Wo_st, bz, bo, slot_z, slot_o);
  hipLaunchKernelGGL(post_kernel, dim3(Bn * NHn), dim3(256), 0, stream, x, cell,
                     norm, maxs, gn_w, gn_b, out);
}

// Round 2
// 1092.715 us; speedup vs baseline: 2.0254x; 2.0254x over previous
//
#include <hip/hip_runtime.h>
#include <math.h>

// SLSTM block step. B=2048 H=4096 NH=4 HS=1024 convK=4
// GEMMs run on matrix cores via bf16x2 split (3 MFMA products, fp32 accum).
// d_out slots (floats, each B*H unless noted):
//   [0*BH) out | [1*BH,4*BH) new_conv_state (B,3,H) | [4*BH) y | [5*BH) cell
//   [6*BH) norm | [7*BH) max
// Stash plan (no d_ws needed):
//   x_act -> out slot (consumed by gemm pass 1, overwritten by post kernel)
//   xn    -> new_conv_state[:,2,:] (IS that output; gemm pass 2 reads stride 3H)
//   gate pre-acts i,f,z,o -> y,cell,norm,max slots (consumed+overwritten by post)

#define Bn 2048
#define Hn 4096
#define NHn 4
#define HSn 1024

typedef __attribute__((ext_vector_type(8))) short short8;
typedef __attribute__((ext_vector_type(4))) float f32x4;
typedef unsigned int uint;

// ---------------------------------------------------------------- prep ------
__global__ __launch_bounds__(256) void prep_kernel(
    const float* __restrict__ x, const float* __restrict__ cs,
    const float* __restrict__ ln_w, const float* __restrict__ conv_w,
    const float* __restrict__ conv_b, float* __restrict__ dout) {
  const int b = blockIdx.x;
  const int t = threadIdx.x;
  const float* xr = x + (size_t)b * Hn;

  float4 xv[4];
  float s = 0.f, s2 = 0.f;
#pragma unroll
  for (int i = 0; i < 4; ++i) {
    xv[i] = *reinterpret_cast<const float4*>(xr + i * 1024 + t * 4);
    s += xv[i].x + xv[i].y + xv[i].z + xv[i].w;
    s2 += xv[i].x * xv[i].x + xv[i].y * xv[i].y + xv[i].z * xv[i].z +
          xv[i].w * xv[i].w;
  }
#pragma unroll
  for (int off = 32; off >= 1; off >>= 1) {
    s += __shfl_down(s, off);
    s2 += __shfl_down(s2, off);
  }
  __shared__ float red[10];
  const int lane = t & 63, wv = t >> 6;
  if (lane == 0) { red[wv] = s; red[4 + wv] = s2; }
  __syncthreads();
  if (t == 0) {
    float ts = red[0] + red[1] + red[2] + red[3];
    float ts2 = red[4] + red[5] + red[6] + red[7];
    float mean = ts * (1.f / Hn);
    float var = ts2 * (1.f / Hn) - mean * mean;
    red[8] = mean;
    red[9] = rsqrtf(var + 1e-5f);
  }
  __syncthreads();
  const float mean = red[8], rstd = red[9];

  float* xact_out = dout;
  float* ncs = dout + (size_t)Bn * Hn;

#pragma unroll
  for (int i = 0; i < 4; ++i) {
    const int h = i * 1024 + t * 4;
    float lw[4], cs0[4], cs1[4], cs2[4], cb[4];
    *(float4*)lw = *(const float4*)(ln_w + h);
    *(float4*)cs0 = *(const float4*)(cs + ((size_t)b * 3 + 0) * Hn + h);
    *(float4*)cs1 = *(const float4*)(cs + ((size_t)b * 3 + 1) * Hn + h);
    *(float4*)cs2 = *(const float4*)(cs + ((size_t)b * 3 + 2) * Hn + h);
    *(float4*)cb = *(const float4*)(conv_b + h);
    const float xvi[4] = {xv[i].x, xv[i].y, xv[i].z, xv[i].w};
    float xnv[4], xav[4];
#pragma unroll
    for (int j = 0; j < 4; ++j) {
      const float xnj = (xvi[j] - mean) * rstd * lw[j];
      float cw[4];
      *(float4*)cw = *(const float4*)(conv_w + (size_t)(h + j) * 4);
      const float xc =
          cs0[j] * cw[0] + cs1[j] * cw[1] + cs2[j] * cw[2] + xnj * cw[3] + cb[j];
      xav[j] = xc / (1.f + expf(-xc));  // silu
      xnv[j] = xnj;
    }
    *(float4*)(xact_out + (size_t)b * Hn + h) = *(float4*)xav;
    *(float4*)(ncs + ((size_t)b * 3 + 0) * Hn + h) = *(float4*)cs1;
    *(float4*)(ncs + ((size_t)b * 3 + 1) * Hn + h) = *(float4*)cs2;
    *(float4*)(ncs + ((size_t)b * 3 + 2) * Hn + h) = *(float4*)xnv;
  }
}

// ------------------------------------------------------- bf16x2 helpers -----
__device__ __forceinline__ void cvt8(const float4 a, const float4 b,
                                     uint4& hi, uint4& lo) {
  float f[8] = {a.x, a.y, a.z, a.w, b.x, b.y, b.z, b.w};
  uint h[8], l_[8];
#pragma unroll
  for (int j = 0; j < 8; ++j) {
    uint u = __float_as_uint(f[j]);
    uint r = u + 0x7FFFu + ((u >> 16) & 1u);         // RNE to bf16
    h[j] = r >> 16;
    float res = f[j] - __uint_as_float(r & 0xFFFF0000u);
    uint u2 = __float_as_uint(res);
    uint r2 = u2 + 0x7FFFu + ((u2 >> 16) & 1u);
    l_[j] = r2 >> 16;
  }
  hi = make_uint4(h[0] | (h[1] << 16), h[2] | (h[3] << 16),
                  h[4] | (h[5] << 16), h[6] | (h[7] << 16));
  lo = make_uint4(l_[0] | (l_[1] << 16), l_[2] | (l_[3] << 16),
                  l_[4] | (l_[5] << 16), l_[6] | (l_[7] << 16));
}

// ---------------------------------------------------------------- gemm ------
// Per block: 256 batch rows x (64 cols of gate0 + 64 cols of gate1), K=2048
// (1024 from Ain x Wg_in then 1024 from Ast x Wg_st). BK=32.
// LDS (48KB): A_hi[256][32] A_lo W_hi[128][32] W_lo, bf16, XOR-swizzled groups.
// 4 waves: wave w: wm=w>>1 (row half), wn=w&1 (gate). Per wave 128x64 output
// = 8x4 fragments of 16x16, 3 MFMA per fragment per K-step (hi*hi+lo*hi+hi*lo).
__global__ __launch_bounds__(256, 2) void gemm_pair_mfma(
    const float* __restrict__ Ain, int lda_in, const float* __restrict__ Ast,
    const float* __restrict__ W0in, const float* __restrict__ W0st,
    const float* __restrict__ W1in, const float* __restrict__ W1st,
    const float* __restrict__ bias0, const float* __restrict__ bias1,
    float* __restrict__ O0, float* __restrict__ O1) {
  __shared__ uint4 ldsbuf[3072];  // 48 KiB
  char* lds = (char*)ldsbuf;
  // layout: A_hi [0,16K) A_lo [16K,32K) W_hi [32K,40K) W_lo [40K,48K)

  const int bid = blockIdx.x;  // 512 blocks, XCD-chunked swizzle (512%8==0)
  const int swz = (bid & 7) * 64 + (bid >> 3);
  const int head = swz >> 7;
  const int rem = swz & 127;
  const int mt = rem >> 4;
  const int nt = rem & 15;
  const int bm0 = mt * 256;
  const int kn0 = nt * 64;

  const int tid = threadIdx.x;
  const int w = tid >> 6;
  const int wm = w >> 1;   // 0..1 row half
  const int wn = w & 1;    // gate
  const int l = tid & 63;
  const int l15 = l & 15;
  const int l4 = l >> 4;

  // LDS write offsets (constant; group swizzle g ^= row&3)
  int awoff[4], wwoff[2];
#pragma unroll
  for (int i = 0; i < 4; ++i) {
    int p = tid + i * 256; int row = p >> 2; int g = p & 3;
    awoff[i] = row * 64 + ((g ^ (row & 3)) * 16);
  }
#pragma unroll
  for (int i = 0; i < 2; ++i) {
    int q = tid + i * 256; int s = q >> 2; int g = q & 3;
    wwoff[i] = 32768 + s * 64 + ((g ^ (s & 3)) * 16);
  }

  // fragment read offsets (row&3 == l&3 since frag row base is mult of 16)
  const int aswz = ((l4 ^ (l & 3)) * 16);
  const int aoff = (wm * 128 + l15) * 64 + aswz;
  const int woff = 32768 + (wn * 64 + l15) * 64 + aswz;

  float4 ra[8];  // A prefetch: 4 pairs x 2 float4
  float4 rw[4];  // W prefetch: 2 pairs x 2 float4

#define GLOAD(T)                                                              \
  {                                                                           \
    const int t_ = (T);                                                       \
    const float* Ap; size_t lda; const float* W0; const float* W1; int kk;    \
    if (t_ < 32) { Ap = Ain; lda = (size_t)lda_in; W0 = W0in; W1 = W1in;      \
                   kk = t_ * 32; }                                            \
    else { Ap = Ast; lda = Hn; W0 = W0st; W1 = W1st; kk = (t_ - 32) * 32; }   \
    const size_t acol = (size_t)head * HSn + kk;                              \
    _Pragma("unroll")                                                         \
    for (int i = 0; i < 4; ++i) {                                             \
      int p = tid + i * 256; int row = p >> 2; int g = p & 3;                 \
      const float* ap = Ap + (size_t)(bm0 + row) * lda + acol + g * 8;        \
      ra[2 * i] = *(const float4*)ap;                                         \
      ra[2 * i + 1] = *(const float4*)(ap + 4);                               \
    }                                                                         \
    const size_t wbase = (size_t)head * (HSn * HSn) + kk;                     \
    _Pragma("unroll")                                                         \
    for (int i = 0; i < 2; ++i) {                                             \
      int q = tid + i * 256; int s = q >> 2; int g = q & 3;                   \
      const float* wp = ((s >> 6) ? W1 : W0) + wbase +                        \
                        (size_t)(kn0 + (s & 63)) * HSn + g * 8;               \
      rw[2 * i] = *(const float4*)wp;                                         \
      rw[2 * i + 1] = *(const float4*)(wp + 4);                               \
    }                                                                         \
  }

#define LWRITE()                                                              \
  {                                                                           \
    _Pragma("unroll")                                                         \
    for (int i = 0; i < 4; ++i) {                                             \
      uint4 hi, lo;                                                           \
      cvt8(ra[2 * i], ra[2 * i + 1], hi, lo);                                 \
      *(uint4*)(lds + awoff[i]) = hi;                                         \
      *(uint4*)(lds + 16384 + awoff[i]) = lo;                                 \
    }                                                                         \
    _Pragma("unroll")                                                         \
    for (int i = 0; i < 2; ++i) {                                             \
      uint4 hi, lo;                                                           \
      cvt8(rw[2 * i], rw[2 * i + 1], hi, lo);                                 \
      *(uint4*)(lds + wwoff[i]) = hi;                                         \
      *(uint4*)(lds + 8192 + wwoff[i]) = lo;                                  \
    }                                                                         \
  }

  f32x4 acc[8][4] = {};

  GLOAD(0);
  LWRITE();
  __syncthreads();

#pragma unroll 1
  for (int t = 0; t < 64; ++t) {
    if (t < 63) GLOAD(t + 1);  // in flight under compute (T14)

    short8 wh[4], wl[4];
#pragma unroll
    for (int nf = 0; nf < 4; ++nf) {
      wh[nf] = *(const short8*)(lds + woff + nf * 1024);
      wl[nf] = *(const short8*)(lds + woff + 8192 + nf * 1024);
    }
#pragma unroll
    for (int mf = 0; mf < 8; ++mf) {
      short8 ah = *(const short8*)(lds + aoff + mf * 1024);
      short8 al = *(const short8*)(lds + aoff + 16384 + mf * 1024);
#pragma unroll
      for (int nf = 0; nf < 4; ++nf) {
        acc[mf][nf] =
            __builtin_amdgcn_mfma_f32_16x16x32_bf16(ah, wh[nf], acc[mf][nf], 0, 0, 0);
        acc[mf][nf] =
            __builtin_amdgcn_mfma_f32_16x16x32_bf16(al, wh[nf], acc[mf][nf], 0, 0, 0);
        acc[mf][nf] =
            __builtin_amdgcn_mfma_f32_16x16x32_bf16(ah, wl[nf], acc[mf][nf], 0, 0, 0);
      }
    }
    __syncthreads();
    if (t < 63) {
      LWRITE();
      __syncthreads();
    }
  }

  // epilogue: bias + store (C/D: col=lane&15, row=(lane>>4)*4+reg)
  float* Og = wn ? O1 : O0;
  const float* bg = wn ? bias1 : bias0;
#pragma unroll
  for (int nf = 0; nf < 4; ++nf) {
    const int ncol = head * HSn + kn0 + nf * 16 + l15;
    const float bv = bg[ncol];
#pragma unroll
    for (int mf = 0; mf < 8; ++mf) {
      const int rbase = bm0 + wm * 128 + mf * 16 + l4 * 4;
#pragma unroll
      for (int j = 0; j < 4; ++j) {
        Og[(size_t)(rbase + j) * Hn + ncol] = acc[mf][nf][j] + bv;
      }
    }
  }
#undef GLOAD
#undef LWRITE
}

// ---------------------------------------------------------------- post ------
__global__ __launch_bounds__(256) void post_kernel(
    const float* __restrict__ x, const float* __restrict__ cell_state,
    const float* __restrict__ norm_state, const float* __restrict__ max_state,
    const float* __restrict__ gn_w, const float* __restrict__ gn_b,
    float* __restrict__ dout) {
  const size_t BH = (size_t)Bn * Hn;
  const int blk = blockIdx.x;
  const int b = blk >> 2;
  const int n = blk & 3;
  const int t = threadIdx.x;
  const int col = n * HSn + t * 4;
  const size_t off = (size_t)b * Hn + col;

  float iv[4], fv[4], zv[4], ov[4], csv[4], nsv[4], msv[4], xv[4];
  *(float4*)iv = *(const float4*)(dout + 4 * BH + off);
  *(float4*)fv = *(const float4*)(dout + 5 * BH + off);
  *(float4*)zv = *(const float4*)(dout + 6 * BH + off);
  *(float4*)ov = *(const float4*)(dout + 7 * BH + off);
  *(float4*)csv = *(const float4*)(cell_state + off);
  *(float4*)nsv = *(const float4*)(norm_state + off);
  *(float4*)msv = *(const float4*)(max_state + off);
  *(float4*)xv = *(const float4*)(x + off);

  float yv[4], cnv[4], nnv[4], mnv[4];
  float s = 0.f, s2 = 0.f;
#pragma unroll
  for (int j = 0; j < 4; ++j) {
    const float fj = fv[j];
    const float ls =
        (fj >= 0.f) ? -log1pf(expf(-fj)) : (fj - log1pf(expf(fj)));
    const float lfm = msv[j] + ls;
    const float mn = fmaxf(iv[j], lfm);
    const float ig = expf(iv[j] - mn);
    const float fg = expf(lfm - mn);
    const float cn = fg * csv[j] + ig * tanhf(zv[j]);
    const float nn = fg * nsv[j] + ig;
    const float so = 1.f / (1.f + expf(-ov[j]));
    const float y = so * cn / (nn + 1e-6f);
    yv[j] = y; cnv[j] = cn; nnv[j] = nn; mnv[j] = mn;
    s += y; s2 += y * y;
  }
  *(float4*)(dout + 4 * BH + off) = *(float4*)yv;
  *(float4*)(dout + 5 * BH + off) = *(float4*)cnv;
  *(float4*)(dout + 6 * BH + off) = *(float4*)nnv;
  *(float4*)(dout + 7 * BH + off) = *(float4*)mnv;

#pragma unroll
  for (int o2 = 32; o2 >= 1; o2 >>= 1) {
    s += __shfl_down(s, o2);
    s2 += __shfl_down(s2, o2);
  }
  __shared__ float red[10];
  const int lane = t & 63, wv = t >> 6;
  if (lane == 0) { red[wv] = s; red[4 + wv] = s2; }
  __syncthreads();
  if (t == 0) {
    float ts = red[0] + red[1] + red[2] + red[3];
    float ts2 = red[4] + red[5] + red[6] + red[7];
    float mean = ts * (1.f / HSn);
    float var = ts2 * (1.f / HSn) - mean * mean;
    red[8] = mean;
    red[9] = rsqrtf(var + 1e-5f);
  }
  __syncthreads();
  const float gm = red[8], grs = red[9];
  float gw[4], gb[4], outv[4];
  *(float4*)gw = *(const float4*)(gn_w + col);
  *(float4*)gb = *(const float4*)(gn_b + col);
#pragma unroll
  for (int j = 0; j < 4; ++j)
    outv[j] = (yv[j] - gm) * grs * gw[j] + gb[j] + xv[j];
  *(float4*)(dout + off) = *(float4*)outv;
}

// --------------------------------------------------------------- launch -----
extern "C" void kernel_launch(void* const* d_in, const int* in_sizes, int n_in,
                              void* d_out, int out_size, void* d_ws,
                              size_t ws_size, hipStream_t stream) {
  const float* x = (const float*)d_in[0];
  const float* cs = (const float*)d_in[1];
  const float* rst = (const float*)d_in[2];
  const float* cell = (const float*)d_in[3];
  const float* norm = (const float*)d_in[4];
  const float* maxs = (const float*)d_in[5];
  const float* ln_w = (const float*)d_in[6];
  const float* conv_w = (const float*)d_in[7];
  const float* conv_b = (const float*)d_in[8];
  const float* Wi_in = (const float*)d_in[9];
  const float* Wf_in = (const float*)d_in[10];
  const float* Wz_in = (const float*)d_in[11];
  const float* Wo_in = (const float*)d_in[12];
  const float* Wi_st = (const float*)d_in[13];
  const float* Wf_st = (const float*)d_in[14];
  const float* Wz_st = (const float*)d_in[15];
  const float* Wo_st = (const float*)d_in[16];
  const float* bi = (const float*)d_in[17];
  const float* bf_ = (const float*)d_in[18];
  const float* bz = (const float*)d_in[19];
  const float* bo = (const float*)d_in[20];
  const float* gn_w = (const float*)d_in[21];
  const float* gn_b = (const float*)d_in[22];

  float* out = (float*)d_out;
  const size_t BH = (size_t)Bn * Hn;
  float* xact = out;
  float* ncs = out + BH;
  const float* xn = ncs + 2 * (size_t)Hn;  // stride 3H rows
  float* slot_i = out + 4 * BH;
  float* slot_f = out + 5 * BH;
  float* slot_z = out + 6 * BH;
  float* slot_o = out + 7 * BH;

  hipLaunchKernelGGL(prep_kernel, dim3(Bn), dim3(256), 0, stream, x, cs, ln_w,
                     conv_w, conv_b, out);
  hipLaunchKernelGGL(gemm_pair_mfma, dim3(512), dim3(256), 0, stream, xact, Hn,
                     rst, Wi_in, Wi_st, Wf_in, Wf_st, bi, bf_, slot_i, slot_f);
  hipLaunchKernelGGL(gemm_pair_mfma, dim3(512), dim3(256), 0, stream, xn,
                     3 * Hn, rst, Wz_in, Wz_st, Wo_in, Wo_st, bz, bo, slot_z,
                     slot_o);
  hipLaunchKernelGGL(post_kernel, dim3(Bn * NHn), dim3(256), 0, stream, x, cell,
                     norm, maxs, gn_w, gn_b, out);
}